// Round 6
// baseline (1179.555 us; speedup 1.0000x reference)
//
#include <hip/hip_runtime.h>
#include <hip/hip_bf16.h>
#include <stdint.h>

typedef _Float16 f16;
typedef _Float16 f16x2 __attribute__((ext_vector_type(2)));
typedef _Float16 f16x4 __attribute__((ext_vector_type(4)));
typedef _Float16 f16x8 __attribute__((ext_vector_type(8)));
typedef float f32x4 __attribute__((ext_vector_type(4)));
typedef int   i32x4 __attribute__((ext_vector_type(4)));

#define T_STEPS 512
#define BATCH   128
#define DD      512

// workspace layout (bytes)
#define XP_OFF  0                          // f16 Xproj [512][128][512] = 67,108,864
#define WF_OFF  (67108864)                 // f16 W_in  [512][512]      =    524,288
#define WHQ_OFF (67108864 + 524288)        // i8  W_h frag-packed       =    262,144
#define SC_OFF  (67108864 + 524288 + 262144) // f32 row scales [512]    =      2,048

__device__ __forceinline__ f16x2 pk(float a, float b) {
    return __builtin_bit_cast(f16x2, __builtin_amdgcn_cvt_pkrtz(a, b));
}

// ---------------------------------------------------------------- prep: Wf (f16 W_in)
__global__ __launch_bounds__(256) void prep_kernel(
        const float* __restrict__ Win, f16* __restrict__ Wf) {
    int idx = blockIdx.x * 256 + threadIdx.x;
    if (idx < 262144) Wf[idx] = (f16)Win[idx];
}

// ------------------------------------------- quantize W_h to i8, frag-packed, per-row scale
// one wave per output row o. A-frag packing: byte index
//   (((w*4+mt)*8+ks)*64 + l)*16 + j  ->  W_h[out][k]
//   out = w*64+mt*16+(l&15), k = ks*64+(l>>4)*16+j
// scales[o] = m/(127*127): dequant of (W/s_w)*(h*127) needs s_w/127.
__global__ __launch_bounds__(64) void quant_kernel(
        const float* __restrict__ Wh, char* __restrict__ Whq, float* __restrict__ scales) {
    const int o = blockIdx.x, t = threadIdx.x;
    const float* row = Wh + (size_t)o * 512;
    float v[8];
    float m = 0.f;
#pragma unroll
    for (int j = 0; j < 8; j++) { v[j] = row[t * 8 + j]; m = fmaxf(m, fabsf(v[j])); }
#pragma unroll
    for (int off = 32; off > 0; off >>= 1) m = fmaxf(m, __shfl_xor(m, off));
    if (t == 0) scales[o] = m * (1.0f / (127.0f * 127.0f));
    const float inv = 127.0f / m;
    const int w = o >> 6, mt = (o >> 4) & 3, rl = o & 15;
    const int k0 = t * 8;
    const int ks = k0 >> 6, q = (k0 >> 4) & 3, j0 = k0 & 15;
    const int l = q * 16 + rl;
    char* dst = Whq + ((size_t)(((w * 4 + mt) * 8 + ks) * 64 + l)) * 16 + j0;
#pragma unroll
    for (int j = 0; j < 8; j++) dst[j] = (char)rintf(v[j] * inv);
}

// ------------------------------------------------- Xproj = X @ Win^T + b_h (f16 out)
// direct-from-global MFMA, register double-buffered prefetch of next k0 tile
__global__ __launch_bounds__(256, 2) void gemm_kernel(
        const float* __restrict__ X, const f16* __restrict__ Wf,
        const float* __restrict__ bias, f16* __restrict__ Xp) {
    const int lane = threadIdx.x & 63, wave = threadIdx.x >> 6;
    const int wm = wave >> 1, wn = wave & 1;
    const int q = lane >> 4, rl = lane & 15;
    const int m0 = blockIdx.y * 128 + wm * 64;
    const int n0 = blockIdx.x * 128 + wn * 64;

    const float* aBase[4];
    const f16*   bBase[4];
#pragma unroll
    for (int i = 0; i < 4; i++) {
        aBase[i] = X  + (size_t)(m0 + i * 16 + rl) * 512 + q * 8;
        bBase[i] = Wf + (size_t)(n0 + i * 16 + rl) * 512 + q * 8;
    }

    float4 aR[4][2]; f16x8 bR[4];
#pragma unroll
    for (int i = 0; i < 4; i++) {
        aR[i][0] = *(const float4*)(aBase[i]);
        aR[i][1] = *(const float4*)(aBase[i] + 4);
        bR[i]    = *(const f16x8*)(bBase[i]);
    }

    f32x4 acc[4][4] = {};
    for (int k0 = 0; k0 < 512; k0 += 32) {
        const int kn = (k0 + 32 < 512) ? k0 + 32 : k0;
        float4 aN[4][2]; f16x8 bN[4];
#pragma unroll
        for (int i = 0; i < 4; i++) {           // prefetch next tile
            aN[i][0] = *(const float4*)(aBase[i] + kn);
            aN[i][1] = *(const float4*)(aBase[i] + kn + 4);
            bN[i]    = *(const f16x8*)(bBase[i] + kn);
        }
        f16x8 af[4];
#pragma unroll
        for (int i = 0; i < 4; i++) {           // convert current A tile
            f16x2 p0 = pk(aR[i][0].x, aR[i][0].y);
            f16x2 p1 = pk(aR[i][0].z, aR[i][0].w);
            f16x2 p2 = pk(aR[i][1].x, aR[i][1].y);
            f16x2 p3 = pk(aR[i][1].z, aR[i][1].w);
            f16x8 tv;
            tv[0] = p0[0]; tv[1] = p0[1]; tv[2] = p1[0]; tv[3] = p1[1];
            tv[4] = p2[0]; tv[5] = p2[1]; tv[6] = p3[0]; tv[7] = p3[1];
            af[i] = tv;
        }
#pragma unroll
        for (int i = 0; i < 4; i++)
#pragma unroll
            for (int j = 0; j < 4; j++)
                acc[i][j] = __builtin_amdgcn_mfma_f32_16x16x32_f16(af[i], bR[j], acc[i][j], 0, 0, 0);
#pragma unroll
        for (int i = 0; i < 4; i++) { aR[i][0] = aN[i][0]; aR[i][1] = aN[i][1]; bR[i] = bN[i]; }
    }
#pragma unroll
    for (int j = 0; j < 4; j++) {
        const int n = n0 + j * 16 + rl;
        const float bn = bias[n];
#pragma unroll
        for (int i = 0; i < 4; i++)
#pragma unroll
            for (int r = 0; r < 4; r++) {
                const int m = m0 + i * 16 + q * 4 + r;
                Xp[(size_t)m * 512 + n] = (f16)(acc[i][j][r] + bn);
            }
    }
}

// ----------------------------------------------------------------- recurrence (i8 MFMA)
// C[out][batch] = Wq @ hq^T per step. 8 WGs x 16 batches; 8 waves, wave w owns
// rows [64w,64w+64). i8 A-frags register-resident. h^T stored in LDS in EXACT
// B-fragment lane order: dword d = ks*256 + l*4 + jc holds h-bytes for
// batch bl=l&15, k = ks*64 + (l>>4)*16 + jc*4 + 0..3.
//   read : lane l -> 16 contiguous bytes at (ks*256 + l*4)*4  [conflict-free]
//   write: (w,mt,bl,q) -> dword w*256 + (mt*16+bl)*4 + q      [banks 2-way, free]
// Double-buffered, 1 barrier/step.
__global__ __launch_bounds__(512, 2) void rnn_kernel(
        const char* __restrict__ Whq, const float* __restrict__ scales,
        const f16* __restrict__ Xp, float* __restrict__ out) {
    const int wg = blockIdx.x;          // 0..7
    const int tid = threadIdx.x;
    const int l = tid & 63, w = tid >> 6;
    const int bl = l & 15;              // batch lane (N / C col)
    const int q = l >> 4;               // k-quad / C row quad
    const int b = wg * 16 + bl;

    __shared__ __align__(16) uint32_t hT[2][2048];   // 8 KB per buffer, frag-ordered

    // register-resident i8 A-fragments: af[mt][ks], 4 dwords each = 128 regs
    i32x4 af[4][8];
    {
        const i32x4* wp = (const i32x4*)Whq;
#pragma unroll
        for (int mt = 0; mt < 4; mt++)
#pragma unroll
            for (int ks = 0; ks < 8; ks++)
                af[mt][ks] = wp[((w * 4 + mt) * 8 + ks) * 64 + l];
    }
    // per-lane output-row scales (already /127^2)
    float sc[4][4];
#pragma unroll
    for (int mt = 0; mt < 4; mt++)
#pragma unroll
        for (int r = 0; r < 4; r++)
            sc[mt][r] = scales[w * 64 + mt * 16 + q * 4 + r];

    for (int i = tid; i < 2048; i += 512) hT[0][i] = 0u;
    __syncthreads();

    const f16* xpb = Xp + (size_t)b * 512 + w * 64 + q * 4;
    f16x4 xn[4];
#pragma unroll
    for (int mt = 0; mt < 4; mt++) xn[mt] = *(const f16x4*)(xpb + mt * 16);

    f32x4 ho[4];                        // last h (f32) for the final store
    for (int t = 0; t < T_STEPS; t++) {
        f16x4 xc[4];
#pragma unroll
        for (int mt = 0; mt < 4; mt++) xc[mt] = xn[mt];
        const size_t tn = (size_t)(t < T_STEPS - 1 ? t + 1 : t) * (BATCH * 512);
#pragma unroll
        for (int mt = 0; mt < 4; mt++) xn[mt] = *(const f16x4*)(xpb + tn + mt * 16);

        const int rb = t & 1;
        i32x4 acc[4] = {};
        const uint32_t* hrow = &hT[rb][l * 4];
#pragma unroll
        for (int ks = 0; ks < 8; ks++) {
            i32x4 bfr = *(const i32x4*)(hrow + ks * 256);
#pragma unroll
            for (int mt = 0; mt < 4; mt++)
                acc[mt] = __builtin_amdgcn_mfma_i32_16x16x64_i8(af[mt][ks], bfr, acc[mt], 0, 0, 0);
        }
        // epilogue: scale, +xp, sigmoid, quantize to i8, write next h^T (frag order)
#pragma unroll
        for (int mt = 0; mt < 4; mt++) {
            float v0 = (float)acc[mt][0] * sc[mt][0] + (float)xc[mt][0];
            float v1 = (float)acc[mt][1] * sc[mt][1] + (float)xc[mt][1];
            float v2 = (float)acc[mt][2] * sc[mt][2] + (float)xc[mt][2];
            float v3 = (float)acc[mt][3] * sc[mt][3] + (float)xc[mt][3];
            float s0 = 1.0f / (1.0f + __expf(-v0));
            float s1 = 1.0f / (1.0f + __expf(-v1));
            float s2 = 1.0f / (1.0f + __expf(-v2));
            float s3 = 1.0f / (1.0f + __expf(-v3));
            ho[mt][0] = s0; ho[mt][1] = s1; ho[mt][2] = s2; ho[mt][3] = s3;
            uint32_t pkq = (uint32_t)(int)(s0 * 127.f + 0.5f)
                         | ((uint32_t)(int)(s1 * 127.f + 0.5f) << 8)
                         | ((uint32_t)(int)(s2 * 127.f + 0.5f) << 16)
                         | ((uint32_t)(int)(s3 * 127.f + 0.5f) << 24);
            hT[1 - rb][w * 256 + (mt * 16 + bl) * 4 + q] = pkq;
        }
        __syncthreads();
    }
#pragma unroll
    for (int mt = 0; mt < 4; mt++)
        *(float4*)(out + (size_t)b * 512 + w * 64 + mt * 16 + q * 4) =
            make_float4(ho[mt][0], ho[mt][1], ho[mt][2], ho[mt][3]);
}

extern "C" void kernel_launch(void* const* d_in, const int* in_sizes, int n_in,
                              void* d_out, int out_size, void* d_ws, size_t ws_size,
                              hipStream_t stream) {
    const float* X   = (const float*)d_in[0];
    const float* Win = (const float*)d_in[1];
    const float* Wh  = (const float*)d_in[2];
    const float* bh  = (const float*)d_in[3];
    float* out = (float*)d_out;
    char* ws = (char*)d_ws;
    f16* Xp      = (f16*)(ws + XP_OFF);
    f16* Wf      = (f16*)(ws + WF_OFF);
    char* Whq    = (char*)(ws + WHQ_OFF);
    float* Sc    = (float*)(ws + SC_OFF);

    prep_kernel<<<1024, 256, 0, stream>>>(Win, Wf);
    quant_kernel<<<512, 64, 0, stream>>>(Wh, Whq, Sc);
    gemm_kernel<<<dim3(4, 512), 256, 0, stream>>>(X, Wf, bh, Xp);
    rnn_kernel<<<8, 512, 0, stream>>>(Whq, Sc, Xp, out);
}

// Round 8
// 1109.819 us; speedup vs baseline: 1.0628x; 1.0628x over previous
//
#include <hip/hip_runtime.h>
#include <hip/hip_bf16.h>
#include <stdint.h>

typedef _Float16 f16;
typedef _Float16 f16x2 __attribute__((ext_vector_type(2)));
typedef _Float16 f16x4 __attribute__((ext_vector_type(4)));
typedef _Float16 f16x8 __attribute__((ext_vector_type(8)));
typedef float f32x4 __attribute__((ext_vector_type(4)));
typedef int   i32x4 __attribute__((ext_vector_type(4)));

#define T_STEPS 512
#define BATCH   128
#define DD      512
#define LOG2E   1.44269504088896f

// workspace layout (bytes)
#define XP_OFF  0                          // f16 Xproj' [512][128][512] = 67,108,864
#define WF_OFF  (67108864)                 // f16 W_in  [512][512]      =    524,288
#define WHQ_OFF (67108864 + 524288)        // i8  W_h frag-packed       =    262,144
#define SC_OFF  (67108864 + 524288 + 262144) // f32 row scales2 [512]   =      2,048

__device__ __forceinline__ f16x2 pk(float a, float b) {
    return __builtin_bit_cast(f16x2, __builtin_amdgcn_cvt_pkrtz(a, b));
}

__device__ __forceinline__ float fast_exp2(float x) {
#if __has_builtin(__builtin_amdgcn_exp2f)
    return __builtin_amdgcn_exp2f(x);
#else
    return exp2f(x);
#endif
}

__device__ __forceinline__ float fast_rcp(float x) {
#if __has_builtin(__builtin_amdgcn_rcpf)
    return __builtin_amdgcn_rcpf(x);
#else
    return 1.0f / x;
#endif
}

__device__ __forceinline__ uint32_t pack_u8(float s, int pos, uint32_t old) {
#if __has_builtin(__builtin_amdgcn_cvt_pk_u8_f32)
    return __builtin_amdgcn_cvt_pk_u8_f32(s, pos, old);
#else
    return old | (((uint32_t)(int)s & 0xFF) << (8 * pos));
#endif
}

// ---------------------------------------------------------------- prep: Wf (f16 W_in)
__global__ __launch_bounds__(256) void prep_kernel(
        const float* __restrict__ Win, f16* __restrict__ Wf) {
    int idx = blockIdx.x * 256 + threadIdx.x;
    if (idx < 262144) Wf[idx] = (f16)Win[idx];
}

// ------------------------------------------- quantize W_h to i8, frag-packed, per-row scale
// one wave per output row o. A-frag packing: byte index
//   (((w*4+mt)*8+ks)*64 + l)*16 + j  ->  W_h[out][k]
//   out = w*64+mt*16+(l&15), k = ks*64+(l>>4)*16+j
// scales2[o] = -log2e * m/(127*127): epilogue computes t = acc*sc2 + xp2 = -log2e*v.
__global__ __launch_bounds__(64) void quant_kernel(
        const float* __restrict__ Wh, char* __restrict__ Whq, float* __restrict__ scales) {
    const int o = blockIdx.x, t = threadIdx.x;
    const float* row = Wh + (size_t)o * 512;
    float v[8];
    float m = 0.f;
#pragma unroll
    for (int j = 0; j < 8; j++) { v[j] = row[t * 8 + j]; m = fmaxf(m, fabsf(v[j])); }
#pragma unroll
    for (int off = 32; off > 0; off >>= 1) m = fmaxf(m, __shfl_xor(m, off));
    if (t == 0) scales[o] = -LOG2E * m * (1.0f / (127.0f * 127.0f));
    const float inv = 127.0f / m;
    const int w = o >> 6, mt = (o >> 4) & 3, rl = o & 15;
    const int k0 = t * 8;
    const int ks = k0 >> 6, q = (k0 >> 4) & 3, j0 = k0 & 15;
    const int l = q * 16 + rl;
    char* dst = Whq + ((size_t)(((w * 4 + mt) * 8 + ks) * 64 + l)) * 16 + j0;
#pragma unroll
    for (int j = 0; j < 8; j++) dst[j] = (char)rintf(v[j] * inv);
}

// ------------------------------------------------- Xproj' = -log2e*(X @ Win^T + b_h), f16
// direct-from-global MFMA, register double-buffered prefetch of next k0 tile
__global__ __launch_bounds__(256, 2) void gemm_kernel(
        const float* __restrict__ X, const f16* __restrict__ Wf,
        const float* __restrict__ bias, f16* __restrict__ Xp) {
    const int lane = threadIdx.x & 63, wave = threadIdx.x >> 6;
    const int wm = wave >> 1, wn = wave & 1;
    const int q = lane >> 4, rl = lane & 15;
    const int m0 = blockIdx.y * 128 + wm * 64;
    const int n0 = blockIdx.x * 128 + wn * 64;

    const float* aBase[4];
    const f16*   bBase[4];
#pragma unroll
    for (int i = 0; i < 4; i++) {
        aBase[i] = X  + (size_t)(m0 + i * 16 + rl) * 512 + q * 8;
        bBase[i] = Wf + (size_t)(n0 + i * 16 + rl) * 512 + q * 8;
    }

    float4 aR[4][2]; f16x8 bR[4];
#pragma unroll
    for (int i = 0; i < 4; i++) {
        aR[i][0] = *(const float4*)(aBase[i]);
        aR[i][1] = *(const float4*)(aBase[i] + 4);
        bR[i]    = *(const f16x8*)(bBase[i]);
    }

    f32x4 acc[4][4] = {};
    for (int k0 = 0; k0 < 512; k0 += 32) {
        const int kn = (k0 + 32 < 512) ? k0 + 32 : k0;
        float4 aN[4][2]; f16x8 bN[4];
#pragma unroll
        for (int i = 0; i < 4; i++) {           // prefetch next tile
            aN[i][0] = *(const float4*)(aBase[i] + kn);
            aN[i][1] = *(const float4*)(aBase[i] + kn + 4);
            bN[i]    = *(const f16x8*)(bBase[i] + kn);
        }
        f16x8 af[4];
#pragma unroll
        for (int i = 0; i < 4; i++) {           // convert current A tile
            f16x2 p0 = pk(aR[i][0].x, aR[i][0].y);
            f16x2 p1 = pk(aR[i][0].z, aR[i][0].w);
            f16x2 p2 = pk(aR[i][1].x, aR[i][1].y);
            f16x2 p3 = pk(aR[i][1].z, aR[i][1].w);
            f16x8 tv;
            tv[0] = p0[0]; tv[1] = p0[1]; tv[2] = p1[0]; tv[3] = p1[1];
            tv[4] = p2[0]; tv[5] = p2[1]; tv[6] = p3[0]; tv[7] = p3[1];
            af[i] = tv;
        }
#pragma unroll
        for (int i = 0; i < 4; i++)
#pragma unroll
            for (int j = 0; j < 4; j++)
                acc[i][j] = __builtin_amdgcn_mfma_f32_16x16x32_f16(af[i], bR[j], acc[i][j], 0, 0, 0);
#pragma unroll
        for (int i = 0; i < 4; i++) { aR[i][0] = aN[i][0]; aR[i][1] = aN[i][1]; bR[i] = bN[i]; }
    }
#pragma unroll
    for (int j = 0; j < 4; j++) {
        const int n = n0 + j * 16 + rl;
        const float bn = bias[n];
#pragma unroll
        for (int i = 0; i < 4; i++)
#pragma unroll
            for (int r = 0; r < 4; r++) {
                const int m = m0 + i * 16 + q * 4 + r;
                Xp[(size_t)m * 512 + n] = (f16)(-LOG2E * (acc[i][j][r] + bn));
            }
    }
}

// ----------------------------------------------------------------- recurrence (i8 MFMA)
// C[out][batch] = Wq @ hq^T per step. 8 WGs x 16 batches; 8 waves, wave w owns
// rows [64w,64w+64). i8 A-frags register-resident. h^T stored in LDS in EXACT
// B-fragment lane order (conflict-free reads/writes, see R6).
// Epilogue per output (VALU-minimal): t = fma(accf, sc2, xp2); e = exp2(t);
// eq = fma(e,1/127,1/127); r = rcp(eq) = 127*sigmoid; pack_u8(r+0.5).
__global__ __launch_bounds__(512, 2) void rnn_kernel(
        const char* __restrict__ Whq, const float* __restrict__ scales,
        const f16* __restrict__ Xp, float* __restrict__ out) {
    const int wg = blockIdx.x;          // 0..7
    const int tid = threadIdx.x;
    const int l = tid & 63, w = tid >> 6;
    const int bl = l & 15;              // batch lane (N / C col)
    const int q = l >> 4;               // k-quad / C row quad
    const int b = wg * 16 + bl;

    __shared__ __align__(16) uint32_t hT[2][2048];   // 8 KB per buffer, frag-ordered

    // register-resident i8 A-fragments: af[mt][ks], 4 dwords each = 128 regs
    i32x4 af[4][8];
    {
        const i32x4* wp = (const i32x4*)Whq;
#pragma unroll
        for (int mt = 0; mt < 4; mt++)
#pragma unroll
            for (int ks = 0; ks < 8; ks++)
                af[mt][ks] = wp[((w * 4 + mt) * 8 + ks) * 64 + l];
    }
    // per-lane output-row scales (pre-folded with -log2e/127^2)
    float sc[4][4];
#pragma unroll
    for (int mt = 0; mt < 4; mt++)
#pragma unroll
        for (int r = 0; r < 4; r++)
            sc[mt][r] = scales[w * 64 + mt * 16 + q * 4 + r];

    for (int i = tid; i < 2048; i += 512) hT[0][i] = 0u;
    __syncthreads();

    const f16* xpb = Xp + (size_t)b * 512 + w * 64 + q * 4;
    f16x4 xn[4];
#pragma unroll
    for (int mt = 0; mt < 4; mt++) xn[mt] = *(const f16x4*)(xpb + mt * 16);

    const float K127 = 1.0f / 127.0f;
    for (int t = 0; t < T_STEPS; t++) {
        f16x4 xc[4];
#pragma unroll
        for (int mt = 0; mt < 4; mt++) xc[mt] = xn[mt];
        const size_t tn = (size_t)(t < T_STEPS - 1 ? t + 1 : t) * (BATCH * 512);
#pragma unroll
        for (int mt = 0; mt < 4; mt++) xn[mt] = *(const f16x4*)(xpb + tn + mt * 16);

        const int rb = t & 1;
        i32x4 acc[4] = {};
        const uint32_t* hrow = &hT[rb][l * 4];
#pragma unroll
        for (int ks = 0; ks < 8; ks++) {
            i32x4 bfr = *(const i32x4*)(hrow + ks * 256);
#pragma unroll
            for (int mt = 0; mt < 4; mt++)
                acc[mt] = __builtin_amdgcn_mfma_i32_16x16x64_i8(af[mt][ks], bfr, acc[mt], 0, 0, 0);
        }
#pragma unroll
        for (int mt = 0; mt < 4; mt++) {
            uint32_t pkq = 0;
#pragma unroll
            for (int r = 0; r < 4; r++) {
                float tt = fmaf((float)acc[mt][r], sc[mt][r], (float)xc[mt][r]);
                float e  = fast_exp2(tt);                // e^{-v}
                float eq = fmaf(e, K127, K127);          // (1+e^{-v})/127
                float sg = fast_rcp(eq) + 0.5f;          // 127*sigmoid + 0.5
                pkq = pack_u8(sg, r, pkq);
            }
            hT[1 - rb][w * 256 + (mt * 16 + bl) * 4 + q] = pkq;
        }
        __syncthreads();
    }
    // final h: read back this lane's own dwords, dequantize i8/127 -> f32
#pragma unroll
    for (int mt = 0; mt < 4; mt++) {
        uint32_t pkq = hT[T_STEPS & 1][w * 256 + (mt * 16 + bl) * 4 + q];
        float4 o;
        o.x = (float)((pkq      ) & 0xFF) * K127;
        o.y = (float)((pkq >>  8) & 0xFF) * K127;
        o.z = (float)((pkq >> 16) & 0xFF) * K127;
        o.w = (float)((pkq >> 24) & 0xFF) * K127;
        *(float4*)(out + (size_t)b * 512 + w * 64 + mt * 16 + q * 4) = o;
    }
}

extern "C" void kernel_launch(void* const* d_in, const int* in_sizes, int n_in,
                              void* d_out, int out_size, void* d_ws, size_t ws_size,
                              hipStream_t stream) {
    const float* X   = (const float*)d_in[0];
    const float* Win = (const float*)d_in[1];
    const float* Wh  = (const float*)d_in[2];
    const float* bh  = (const float*)d_in[3];
    float* out = (float*)d_out;
    char* ws = (char*)d_ws;
    f16* Xp      = (f16*)(ws + XP_OFF);
    f16* Wf      = (f16*)(ws + WF_OFF);
    char* Whq    = (char*)(ws + WHQ_OFF);
    float* Sc    = (float*)(ws + SC_OFF);

    prep_kernel<<<1024, 256, 0, stream>>>(Win, Wf);
    quant_kernel<<<512, 64, 0, stream>>>(Wh, Whq, Sc);
    gemm_kernel<<<dim3(4, 512), 256, 0, stream>>>(X, Wf, bh, Xp);
    rnn_kernel<<<8, 512, 0, stream>>>(Whq, Sc, Xp, out);
}